// Round 5
// baseline (4525.552 us; speedup 1.0000x reference)
//
#include <hip/hip_runtime.h>
#include <math.h>

// Problem constants (4, 19, 512, 512) fp32
#define BB 4
#define CC 19
#define HH 512
#define WW 512
#define NSLICE (BB * CC)        // 76
#define SLICE  (HH * WW)        // 262144
#define W4     (WW / 4)         // 128 float4 per row
#define EPS    1e-12f
#define NEGINF (-INFINITY)

// time-tiling params
#define TSTEPS 16
#define RROWS  64
#define AROWS  96               // RROWS + 2*TSTEPS
#define NPASS  16               // 256 / TSTEPS
#define RBLK   8                // HH / RROWS

// REGISTER BUDGET MODEL (verified R0-R4): block of T threads ->
// ceil(T/64/4) waves/EU -> total regs = 512/that, split half arch-VGPR /
// half AGPR; VGPR_Count reports the arch half.
//   512  -> 256 total (VGPR_Count 128)   [R0 clean]
//   768  -> ~168 total (VGPR_Count 84)   [R4: 128-float state + transients
//                                         > 168 -> scratch, WRITE 180MB]
//   1024 -> 128 total (VGPR_Count 64)    [R1-R3: 96-float state -> scratch]
//
// STRUCTURAL FIX (R5): persistent tile state was AROWS*512*2 arrays (c AND
// x) = 96K floats = 75% of the CU register file no matter the block shape.
// x is read-only and t-invariant -> stream it from L2/L3 every step instead
// of holding it (FETCH counters show x is already fully cache-absorbed).
// c-only state = 48 floats/thread at 1024 thr -> fits the 128 budget with
// headroom -> no scratch AND 4 waves/SIMD (2x R0's occupancy).
// LICM hazard: x loads are t-invariant; an empty asm clobber on the offsets
// each step stops the compiler hoisting 48 x-floats back into registers.
#define NW   16                 // waves (strips) per block
#define ROWS 6                  // rows per thread
#define THREADS 1024

// ---------------------------------------------------------------------------
__global__ void init_kernel(const float* __restrict__ x, float* __restrict__ cur) {
    int t = blockIdx.x * blockDim.x + threadIdx.x;
    const float4* x4 = (const float4*)x;
    float4* c4 = (float4*)cur;
    float4 v = x4[t];
    int pix = t << 2;
    int s = pix & (SLICE - 1);
    int i = s >> 9;
    int j0 = s & 511;
    float4 o;
    o.x = -v.x; o.y = -v.y; o.z = -v.z; o.w = -v.w;
    if (i == 0 || i == HH - 1) {
        o.x = 1.0f; o.y = 1.0f; o.z = 1.0f; o.w = 1.0f;
    } else {
        if (j0 == 0)        o.x = 1.0f;
        if (j0 == WW - 4)   o.w = 1.0f;
    }
    c4[t] = o;
}

// ---------------------------------------------------------------------------
// one pass = TSTEPS fused (maxpool3x3 * x) steps on a 512x96 tile.
//  * c-tile in registers (48 floats/thread); x STREAMED from cache per step.
//  * double-buffered LDS halo snapshot -> ONE __syncthreads per step.
//  * separable pool, vertical-first max3; 2 shuffles/row horizontal.
//  * in-place update via 1-row "pend" buffer.
__global__ __launch_bounds__(THREADS)
void pass_kernel(const float* __restrict__ in, const float* __restrict__ xg,
                 float* __restrict__ out) {
    const int tid  = threadIdx.x;
    const int lane = tid & 63;          // column group (8 cols each)
    const int w    = tid >> 6;          // wave = strip index 0..15
    const int bc   = blockIdx.x / RBLK;
    const int brow = blockIdx.x % RBLK;
    const int gstart = brow * RROWS - TSTEPS;       // tile row a=0 -> global row
    const int row0   = gstart + w * ROWS;           // this thread's r=0 global row
    const int col0   = lane * 8;
    const size_t sbase = (size_t)bc * SLICE;
    const float* xb = xg + sbase;       // SGPR base; per-thread int offsets

    // double-buffered top/bottom row snapshots; lane stride 16B ->
    // conflict-free ds_read/write_b128. 128 KiB -> 1 block/CU, 16 waves
    // = 4 waves/SIMD.
    __shared__ float4 Tb[2][NW][2][64];
    __shared__ float4 Bb[2][NW][2][64];

    const float4 neg4 = make_float4(NEGINF, NEGINF, NEGINF, NEGINF);

    float4 cl[ROWS], cr[ROWS];
    int xoff[ROWS];                     // row-clamped float offset of (row, col0)

#pragma unroll
    for (int r = 0; r < ROWS; ++r) {
        int grow = row0 + r;
        int gcl  = min(max(grow, 0), HH - 1);       // clamp for x address
        xoff[r] = gcl * WW + col0;
        if (grow >= 0 && grow < HH) {               // wave-uniform branch
            const float4* p = (const float4*)(in + sbase + (size_t)grow * WW + col0);
            cl[r] = p[0]; cr[r] = p[1];
        } else { cl[r] = neg4; cr[r] = neg4; }
    }

    for (int t = 0; t < TSTEPS; ++t) {
        const int buf = t & 1;
        // break t-invariance of x addresses so LICM can't hoist 48 x-floats
        // out of the t-loop (that would recreate the R1-R4 register spill)
#pragma unroll
        for (int r = 0; r < ROWS; ++r) asm volatile("" : "+v"(xoff[r]));

        // snapshot pre-step top/bottom rows for vertical neighbors
        Tb[buf][w][0][lane] = cl[0];
        Tb[buf][w][1][lane] = cr[0];
        Bb[buf][w][0][lane] = cl[ROWS - 1];
        Bb[buf][w][1][lane] = cr[ROWS - 1];
        __syncthreads();

        // read both halo rows right after the barrier so the ds_read latency
        // hides under the interior-row compute
        float4 upL, upR, dnL, dnR;
        if (w > 0) {                     // wave-uniform
            upL = Bb[buf][w - 1][0][lane];
            upR = Bb[buf][w - 1][1][lane];
        } else { upL = neg4; upR = neg4; }
        if (w < NW - 1) {
            dnL = Tb[buf][w + 1][0][lane];
            dnR = Tb[buf][w + 1][1][lane];
        } else { dnL = neg4; dnR = neg4; }

        float4 pendL, pendR;             // finished value of previous row
#pragma unroll
        for (int r = 0; r < ROWS; ++r) {
            // neighbor rows (pre-step values)
            float4 am1L = (r == 0)        ? upL : cl[r - 1];
            float4 am1R = (r == 0)        ? upR : cr[r - 1];
            float4 ap1L = (r == ROWS - 1) ? dnL : cl[r + 1];
            float4 ap1R = (r == ROWS - 1) ? dnR : cr[r + 1];

            // vertical 3-max (v_max3_f32)
            float4 vl, vr;
            vl.x = fmaxf(fmaxf(am1L.x, cl[r].x), ap1L.x);
            vl.y = fmaxf(fmaxf(am1L.y, cl[r].y), ap1L.y);
            vl.z = fmaxf(fmaxf(am1L.z, cl[r].z), ap1L.z);
            vl.w = fmaxf(fmaxf(am1L.w, cl[r].w), ap1L.w);
            vr.x = fmaxf(fmaxf(am1R.x, cr[r].x), ap1R.x);
            vr.y = fmaxf(fmaxf(am1R.y, cr[r].y), ap1R.y);
            vr.z = fmaxf(fmaxf(am1R.z, cr[r].z), ap1R.z);
            vr.w = fmaxf(fmaxf(am1R.w, cr[r].w), ap1R.w);
            // horizontal 3-max: 2 in-wave shuffles per row
            float lpx = __shfl_up(vr.w, 1);
            float rpx = __shfl_down(vl.x, 1);
            if (lane == 0)  lpx = NEGINF;    // image left pad
            if (lane == 63) rpx = NEGINF;    // image right pad
            // streamed x for this row (L2/L3-resident)
            float4 xlv = *(const float4*)(xb + xoff[r]);
            float4 xrv = *(const float4*)(xb + xoff[r] + 4);
            float4 hl, hr;
            hl.x = fmaxf(fmaxf(lpx,  vl.x), vl.y) * xlv.x;
            hl.y = fmaxf(fmaxf(vl.x, vl.y), vl.z) * xlv.y;
            hl.z = fmaxf(fmaxf(vl.y, vl.z), vl.w) * xlv.z;
            hl.w = fmaxf(fmaxf(vl.z, vl.w), vr.x) * xlv.w;
            hr.x = fmaxf(fmaxf(vl.w, vr.x), vr.y) * xrv.x;
            hr.y = fmaxf(fmaxf(vr.x, vr.y), vr.z) * xrv.y;
            hr.z = fmaxf(fmaxf(vr.y, vr.z), vr.w) * xrv.z;
            hr.w = fmaxf(fmaxf(vr.z, vr.w), rpx)  * xrv.w;
            // out-of-image rows stay -inf (clamp folded into commit)
            {
                int grow = row0 + r;                 // wave-uniform
                if (grow < 0 || grow >= HH) { hl = neg4; hr = neg4; }
            }
            // commit previous row (so row r+1 still reads pre-step c[r])
            if (r > 0) { cl[r - 1] = pendL; cr[r - 1] = pendR; }
            pendL = hl; pendR = hr;
        }
        cl[ROWS - 1] = pendL; cr[ROWS - 1] = pendR;
        // no trailing barrier: next step writes the OTHER buffer; this
        // buffer is rewritten only after the next step's barrier.
    }

    // store valid center rows: tile rows a in [TSTEPS, TSTEPS+RROWS)
#pragma unroll
    for (int r = 0; r < ROWS; ++r) {
        int a = w * ROWS + r;            // wave-uniform condition
        if (a >= TSTEPS && a < TSTEPS + RROWS) {
            int grow = row0 + r;
            float4* p = (float4*)(out + sbase + (size_t)grow * WW + col0);
            p[0] = cl[r]; p[1] = cr[r];
        }
    }
}

// ---------------------------------------------------------------------------
// final: norm over channel dim (19), out = cur * x / max(||cur||_2, eps)
__global__ void norm_kernel(const float* __restrict__ cur,
                            const float* __restrict__ x,
                            float* __restrict__ out) {
    int t = blockIdx.x * blockDim.x + threadIdx.x;
    int j4 = t & (W4 - 1);
    int i  = (t >> 7) & (HH - 1);
    int b  = t >> 16;
    size_t off = (size_t)b * CC * SLICE + (size_t)i * WW + (j4 << 2);

    float4 vals[CC];
    float sx = 0.f, sy = 0.f, sz = 0.f, sw = 0.f;
#pragma unroll
    for (int c = 0; c < CC; ++c) {
        float4 v = *(const float4*)(cur + off + (size_t)c * SLICE);
        vals[c] = v;
        sx += v.x * v.x; sy += v.y * v.y; sz += v.z * v.z; sw += v.w * v.w;
    }
    float4 r;
    r.x = 1.0f / fmaxf(sqrtf(sx), EPS);
    r.y = 1.0f / fmaxf(sqrtf(sy), EPS);
    r.z = 1.0f / fmaxf(sqrtf(sz), EPS);
    r.w = 1.0f / fmaxf(sqrtf(sw), EPS);
#pragma unroll
    for (int c = 0; c < CC; ++c) {
        float4 xv = *(const float4*)(x + off + (size_t)c * SLICE);
        float4 o;
        o.x = vals[c].x * xv.x * r.x;
        o.y = vals[c].y * xv.y * r.y;
        o.z = vals[c].z * xv.z * r.z;
        o.w = vals[c].w * xv.w * r.w;
        *(float4*)(out + off + (size_t)c * SLICE) = o;
    }
}

// ---------------------------------------------------------------------------
extern "C" void kernel_launch(void* const* d_in, const int* in_sizes, int n_in,
                              void* d_out, int out_size, void* d_ws, size_t ws_size,
                              hipStream_t stream) {
    const float* x = (const float*)d_in[0];
    float* out = (float*)d_out;
    float* ws  = (float*)d_ws;        // >= 79,691,776 B

    const int initBlocks = NSLICE * SLICE / 4 / 256; // 19456
    const int passBlocks = NSLICE * RBLK;            // 608
    const int normBlocks = BB * HH * W4 / 256;       // 1024

    init_kernel<<<initBlocks, 256, 0, stream>>>(x, ws);
    float* a = ws;
    float* b = out;
    for (int it = 0; it < NPASS; ++it) {
        pass_kernel<<<passBlocks, THREADS, 0, stream>>>(a, x, b);
        float* tmp = a; a = b; b = tmp;
    }
    // NPASS even -> result back in ws
    norm_kernel<<<normBlocks, 256, 0, stream>>>(ws, x, out);
}

// Round 6
// 4219.468 us; speedup vs baseline: 1.0725x; 1.0725x over previous
//
#include <hip/hip_runtime.h>
#include <math.h>

// Problem constants (4, 19, 512, 512) fp32
#define BB 4
#define CC 19
#define HH 512
#define WW 512
#define NSLICE (BB * CC)        // 76
#define SLICE  (HH * WW)        // 262144
#define W4     (WW / 4)         // 128 float4 per row
#define EPS    1e-12f
#define NEGINF (-INFINITY)

// time-tiling params
#define TSTEPS 16
#define RROWS  64
#define AROWS  96               // RROWS + 2*TSTEPS
#define NPASS  16               // 256 / TSTEPS
#define RBLK   8                // HH / RROWS

// REGISTER BUDGET MODEL (verified R0-R5): block of T threads ->
// ceil(T/64/4) waves/EU -> total regs = 512/that (half arch-VGPR, half AGPR;
// VGPR_Count reports the arch half).
//   512  -> 256 total: R0 held 192 floats/thread (c AND x) with NO spill.
//   768  -> ~168 total: 128-float state spilled (R4).
//   1024 -> 128 total: 96-float state spilled (R1-R3); 48-float fits (R5)
//           but x must then be streamed -> 6.3MB/XCD working set thrashes
//           L2 -> 815 MB HBM fetch/pass, fetch-bound at 278us (R5).
// CONCLUSION: the 96x512 tile's c+x state is 75% of the CU register file;
// 2 waves/SIMD is structural. Keep R0's clean 512-thr register config and
// minimize per-step work instead.
#define NW   8                  // waves (strips) per block
#define ROWS 12                 // rows per thread
#define THREADS 512

// ---------------------------------------------------------------------------
__global__ void init_kernel(const float* __restrict__ x, float* __restrict__ cur) {
    int t = blockIdx.x * blockDim.x + threadIdx.x;
    const float4* x4 = (const float4*)x;
    float4* c4 = (float4*)cur;
    float4 v = x4[t];
    int pix = t << 2;
    int s = pix & (SLICE - 1);
    int i = s >> 9;
    int j0 = s & 511;
    float4 o;
    o.x = -v.x; o.y = -v.y; o.z = -v.z; o.w = -v.w;
    if (i == 0 || i == HH - 1) {
        o.x = 1.0f; o.y = 1.0f; o.z = 1.0f; o.w = 1.0f;
    } else {
        if (j0 == 0)        o.x = 1.0f;
        if (j0 == WW - 4)   o.w = 1.0f;
    }
    c4[t] = o;
}

// ---------------------------------------------------------------------------
// one pass = TSTEPS fused (maxpool3x3 * x) steps on a 512x96 tile.
//
// vs R0 (158.7us/pass, proven-clean 512-thr register config):
//  * separable pool VERTICAL FIRST: v[r]=max3(c[r-1],c[r],c[r+1]) from the
//    persistent register array, then ONE horizontal max3 pass (2 shuffles
//    per row), then *x.  R0 ran hrow() on 3 rows per output row (~2x the
//    max work) -- this body is ~45% fewer max ops.
//  * double-buffered LDS halo snapshot -> ONE __syncthreads per step
//    (step t reads buf[t&1]; buf t&1 is rewritten only at step t+2, after
//    barrier t+1, which happens-after all step-t reads drained).
//  * up-halo read immediately after barrier (needed at r=0); dn-halo read
//    LAZILY at r=ROWS-1 (a whole body later -> ds latency fully hidden, no
//    long-lived registers).
//  * XCD-chunked block swizzle (608 = 8 XCDs x 76): the 8 row-blocks of a
//    slice land on one XCD -> shared halo rows hit that XCD's L2.
//  * in-place update via 1-row "pend" buffer; out-of-image clamp folded
//    into the commit.
__global__ __launch_bounds__(THREADS)
void pass_kernel(const float* __restrict__ in, const float* __restrict__ xg,
                 float* __restrict__ out) {
    const int tid  = threadIdx.x;
    const int lane = tid & 63;          // column group (8 cols each)
    const int w    = tid >> 6;          // wave = strip index 0..7
    // bijective XCD-chunked swizzle: nwg = 608 = 8*76; blocks with equal
    // (blockIdx%8) share an XCD and get 76 consecutive logical ids
    const int nwg  = NSLICE * RBLK;     // 608
    const int g    = (blockIdx.x & 7) * (nwg >> 3) + (blockIdx.x >> 3);
    const int bc   = g / RBLK;
    const int brow = g % RBLK;
    const int gstart = brow * RROWS - TSTEPS;       // tile row a=0 -> global row
    const int row0   = gstart + w * ROWS;           // this thread's r=0 global row
    const int col0   = lane * 8;
    const size_t sbase = (size_t)bc * SLICE;

    // double-buffered top/bottom row snapshots; lane stride 16B ->
    // conflict-free ds_read/write_b128. 64 KiB total.
    __shared__ float4 Tb[2][NW][2][64];
    __shared__ float4 Bb[2][NW][2][64];

    const float4 neg4 = make_float4(NEGINF, NEGINF, NEGINF, NEGINF);
    const float4 one4 = make_float4(1.f, 1.f, 1.f, 1.f);

    float4 cl[ROWS], cr[ROWS], xl[ROWS], xr_[ROWS];

#pragma unroll
    for (int r = 0; r < ROWS; ++r) {
        int grow = row0 + r;
        if (grow >= 0 && grow < HH) {               // wave-uniform branch
            const float4* p = (const float4*)(in + sbase + (size_t)grow * WW + col0);
            cl[r] = p[0]; cr[r] = p[1];
            const float4* q = (const float4*)(xg + sbase + (size_t)grow * WW + col0);
            xl[r] = q[0]; xr_[r] = q[1];
        } else {
            cl[r] = neg4; cr[r] = neg4; xl[r] = one4; xr_[r] = one4;
        }
    }

    for (int t = 0; t < TSTEPS; ++t) {
        const int buf = t & 1;
        // snapshot pre-step top/bottom rows for vertical neighbors
        Tb[buf][w][0][lane] = cl[0];
        Tb[buf][w][1][lane] = cr[0];
        Bb[buf][w][0][lane] = cl[ROWS - 1];
        Bb[buf][w][1][lane] = cr[ROWS - 1];
        __syncthreads();

        // up-halo needed immediately at r=0
        float4 upL, upR;
        if (w > 0) {                     // wave-uniform
            upL = Bb[buf][w - 1][0][lane];
            upR = Bb[buf][w - 1][1][lane];
        } else { upL = neg4; upR = neg4; }

        float4 pendL, pendR;             // finished value of previous row
#pragma unroll
        for (int r = 0; r < ROWS; ++r) {
            // neighbor rows (pre-step values)
            float4 am1L = (r == 0) ? upL : cl[r - 1];
            float4 am1R = (r == 0) ? upR : cr[r - 1];
            float4 ap1L, ap1R;
            if (r == ROWS - 1) {         // dn-halo read lazily (wave-uniform)
                if (w < NW - 1) {
                    ap1L = Tb[buf][w + 1][0][lane];
                    ap1R = Tb[buf][w + 1][1][lane];
                } else { ap1L = neg4; ap1R = neg4; }
            } else { ap1L = cl[r + 1]; ap1R = cr[r + 1]; }

            // vertical 3-max (v_max3_f32)
            float4 vl, vr;
            vl.x = fmaxf(fmaxf(am1L.x, cl[r].x), ap1L.x);
            vl.y = fmaxf(fmaxf(am1L.y, cl[r].y), ap1L.y);
            vl.z = fmaxf(fmaxf(am1L.z, cl[r].z), ap1L.z);
            vl.w = fmaxf(fmaxf(am1L.w, cl[r].w), ap1L.w);
            vr.x = fmaxf(fmaxf(am1R.x, cr[r].x), ap1R.x);
            vr.y = fmaxf(fmaxf(am1R.y, cr[r].y), ap1R.y);
            vr.z = fmaxf(fmaxf(am1R.z, cr[r].z), ap1R.z);
            vr.w = fmaxf(fmaxf(am1R.w, cr[r].w), ap1R.w);
            // horizontal 3-max: 2 in-wave shuffles per row
            float lpx = __shfl_up(vr.w, 1);
            float rpx = __shfl_down(vl.x, 1);
            if (lane == 0)  lpx = NEGINF;    // image left pad
            if (lane == 63) rpx = NEGINF;    // image right pad
            float4 hl, hr;
            hl.x = fmaxf(fmaxf(lpx,  vl.x), vl.y) * xl[r].x;
            hl.y = fmaxf(fmaxf(vl.x, vl.y), vl.z) * xl[r].y;
            hl.z = fmaxf(fmaxf(vl.y, vl.z), vl.w) * xl[r].z;
            hl.w = fmaxf(fmaxf(vl.z, vl.w), vr.x) * xl[r].w;
            hr.x = fmaxf(fmaxf(vl.w, vr.x), vr.y) * xr_[r].x;
            hr.y = fmaxf(fmaxf(vr.x, vr.y), vr.z) * xr_[r].y;
            hr.z = fmaxf(fmaxf(vr.y, vr.z), vr.w) * xr_[r].z;
            hr.w = fmaxf(fmaxf(vr.z, vr.w), rpx)  * xr_[r].w;
            // out-of-image rows stay -inf (clamp folded into commit)
            {
                int grow = row0 + r;                 // wave-uniform
                if (grow < 0 || grow >= HH) { hl = neg4; hr = neg4; }
            }
            // commit previous row (so row r+1 still reads pre-step c[r])
            if (r > 0) { cl[r - 1] = pendL; cr[r - 1] = pendR; }
            pendL = hl; pendR = hr;
        }
        cl[ROWS - 1] = pendL; cr[ROWS - 1] = pendR;
        // no trailing barrier: next step writes the OTHER buffer; this
        // buffer is rewritten only after the next step's barrier.
    }

    // store valid center rows: tile rows a in [TSTEPS, TSTEPS+RROWS)
#pragma unroll
    for (int r = 0; r < ROWS; ++r) {
        int a = w * ROWS + r;            // wave-uniform condition
        if (a >= TSTEPS && a < TSTEPS + RROWS) {
            int grow = row0 + r;
            float4* p = (float4*)(out + sbase + (size_t)grow * WW + col0);
            p[0] = cl[r]; p[1] = cr[r];
        }
    }
}

// ---------------------------------------------------------------------------
// final: norm over channel dim (19), out = cur * x / max(||cur||_2, eps)
__global__ void norm_kernel(const float* __restrict__ cur,
                            const float* __restrict__ x,
                            float* __restrict__ out) {
    int t = blockIdx.x * blockDim.x + threadIdx.x;
    int j4 = t & (W4 - 1);
    int i  = (t >> 7) & (HH - 1);
    int b  = t >> 16;
    size_t off = (size_t)b * CC * SLICE + (size_t)i * WW + (j4 << 2);

    float4 vals[CC];
    float sx = 0.f, sy = 0.f, sz = 0.f, sw = 0.f;
#pragma unroll
    for (int c = 0; c < CC; ++c) {
        float4 v = *(const float4*)(cur + off + (size_t)c * SLICE);
        vals[c] = v;
        sx += v.x * v.x; sy += v.y * v.y; sz += v.z * v.z; sw += v.w * v.w;
    }
    float4 r;
    r.x = 1.0f / fmaxf(sqrtf(sx), EPS);
    r.y = 1.0f / fmaxf(sqrtf(sy), EPS);
    r.z = 1.0f / fmaxf(sqrtf(sz), EPS);
    r.w = 1.0f / fmaxf(sqrtf(sw), EPS);
#pragma unroll
    for (int c = 0; c < CC; ++c) {
        float4 xv = *(const float4*)(x + off + (size_t)c * SLICE);
        float4 o;
        o.x = vals[c].x * xv.x * r.x;
        o.y = vals[c].y * xv.y * r.y;
        o.z = vals[c].z * xv.z * r.z;
        o.w = vals[c].w * xv.w * r.w;
        *(float4*)(out + off + (size_t)c * SLICE) = o;
    }
}

// ---------------------------------------------------------------------------
extern "C" void kernel_launch(void* const* d_in, const int* in_sizes, int n_in,
                              void* d_out, int out_size, void* d_ws, size_t ws_size,
                              hipStream_t stream) {
    const float* x = (const float*)d_in[0];
    float* out = (float*)d_out;
    float* ws  = (float*)d_ws;        // >= 79,691,776 B

    const int initBlocks = NSLICE * SLICE / 4 / 256; // 19456
    const int passBlocks = NSLICE * RBLK;            // 608
    const int normBlocks = BB * HH * W4 / 256;       // 1024

    init_kernel<<<initBlocks, 256, 0, stream>>>(x, ws);
    float* a = ws;
    float* b = out;
    for (int it = 0; it < NPASS; ++it) {
        pass_kernel<<<passBlocks, THREADS, 0, stream>>>(a, x, b);
        float* tmp = a; a = b; b = tmp;
    }
    // NPASS even -> result back in ws
    norm_kernel<<<normBlocks, 256, 0, stream>>>(ws, x, out);
}

// Round 7
// 2218.315 us; speedup vs baseline: 2.0401x; 1.9021x over previous
//
#include <hip/hip_runtime.h>
#include <math.h>

// Problem constants (4, 19, 512, 512) fp32
#define BB 4
#define CC 19
#define HH 512
#define WW 512
#define NSLICE (BB * CC)        // 76
#define SLICE  (HH * WW)        // 262144
#define W4     (WW / 4)         // 128 float4 per row
#define EPS    1e-12f
#define NEGINF (-INFINITY)

// time-tiling params
#define TSTEPS 16
#define RROWS  64
#define AROWS  96               // RROWS + 2*TSTEPS
#define NPASS  16               // 256 / TSTEPS
#define RBLK   8                // HH / RROWS

// thread geometry: 64 lanes x (8 cols each) x 8 waves x (12 rows each).
//
// HISTORY (what is PROVEN on this problem):
//  * Register budget: block of T threads -> ceil(T/64/4) waves/EU ->
//    total regs 512/that (half arch-VGPR half AGPR; VGPR_Count shows arch
//    half). 512thr=256 total. R0's exact body held 192 floats/thread CLEAN
//    (WRITE 97MB). Every deviation (1024thr R1-R3, 768thr R4, x-streaming
//    R5, vertical-first/pend body R6) spilled or thrashed L2.
//  * R6 lesson: vertical-first + deferred-commit extends cl[] live ranges
//    (read at r-1,r,r+1) -> memory spill at the same thread geometry where
//    R0's rolling hA/hB/hC (each row consumed once) allocates clean.
//    => keep R0's body VERBATIM.
//  * R0's stall profile: VALUBusy 33%, HBM 17%, conflicts 0 -> the missing
//    time is DS latency: __shfl == ds_bpermute, 28 per step per wave, at
//    only 2 waves/SIMD. R7 replaces them with DPP wave_shr/shl (full-rate
//    VALU, no LDS) and drops one barrier/step via double-buffered halos.
#define TX   64
#define TY   8
#define COLS 8
#define ROWS 12
#define THREADS 512

struct F8 { float4 a, b; };

// DPP lane shifts (gfx9-family wave_shr:1 / wave_shl:1 -- valid on gfx950).
// bound_ctrl=false keeps `old` in the invalid edge lane, so passing
// old=-inf gives the image-pad value for free (no cndmask fixups).
__device__ __forceinline__ float dpp_up(float src) {   // lane i <- lane i-1; lane0 -> -inf
    int o = __builtin_amdgcn_update_dpp(__float_as_int(NEGINF), __float_as_int(src),
                                        0x138 /*wave_shr:1*/, 0xF, 0xF, false);
    return __int_as_float(o);
}
__device__ __forceinline__ float dpp_dn(float src) {   // lane i <- lane i+1; lane63 -> -inf
    int o = __builtin_amdgcn_update_dpp(__float_as_int(NEGINF), __float_as_int(src),
                                        0x130 /*wave_shl:1*/, 0xF, 0xF, false);
    return __int_as_float(o);
}

// ---------------------------------------------------------------------------
__global__ void init_kernel(const float* __restrict__ x, float* __restrict__ cur) {
    int t = blockIdx.x * blockDim.x + threadIdx.x;
    const float4* x4 = (const float4*)x;
    float4* c4 = (float4*)cur;
    float4 v = x4[t];
    int pix = t << 2;
    int s = pix & (SLICE - 1);
    int i = s >> 9;
    int j0 = s & 511;
    float4 o;
    o.x = -v.x; o.y = -v.y; o.z = -v.z; o.w = -v.w;
    if (i == 0 || i == HH - 1) {
        o.x = 1.0f; o.y = 1.0f; o.z = 1.0f; o.w = 1.0f;
    } else {
        if (j0 == 0)        o.x = 1.0f;
        if (j0 == WW - 4)   o.w = 1.0f;
    }
    c4[t] = o;
}

// ---------------------------------------------------------------------------
// one pass = TSTEPS fused (maxpool3x3 * x) steps on a 512x96 tile.
// R0 structure verbatim except: (1) __shfl -> DPP (no DS ops in hrow),
// (2) double-buffered halo snapshot -> ONE __syncthreads per step,
// (3) XCD-chunked block swizzle for halo-overlap L2 reuse.
__global__ __launch_bounds__(THREADS, 1)
void pass_kernel(const float* __restrict__ in, const float* __restrict__ xg,
                 float* __restrict__ out) {
    const int tid  = threadIdx.x;
    const int tx   = tid & 63;          // lane = column group
    const int ty   = tid >> 6;          // wave = thread-row
    // bijective XCD-chunked swizzle: 608 = 8 XCDs x 76. HW round-robins
    // blocks to XCDs by blockIdx%8, so XCD j gets logical ids [76j,76j+76)
    // = ~9.5 whole slices incl. all 8 row-blocks -> halo overlaps L2-hit.
    const int g    = (blockIdx.x & 7) * (NSLICE * RBLK / 8) + (blockIdx.x >> 3);
    const int bc   = g / RBLK;
    const int brow = g % RBLK;
    const int gstart = brow * RROWS - TSTEPS;       // tile row a=0 -> global row
    const int row0   = gstart + ty * ROWS;          // this thread's r=0 global row
    const int col0   = tx * COLS;
    const size_t sbase = (size_t)bc * SLICE;

    // LDS halo exchange: 8 floats per thread, 9-word lane stride (R0's
    // proven layout), double-buffered -> one barrier per step. 72 KiB.
    __shared__ float Tb[2][TY][TX * 9];
    __shared__ float Bb[2][TY][TX * 9];

    const float4 neg4 = make_float4(NEGINF, NEGINF, NEGINF, NEGINF);
    const float4 one4 = make_float4(1.f, 1.f, 1.f, 1.f);

    float4 cl[ROWS], cr[ROWS], xl[ROWS], xr_[ROWS];

#pragma unroll
    for (int r = 0; r < ROWS; ++r) {
        int grow = row0 + r;
        if (grow >= 0 && grow < HH) {               // wave-uniform branch
            const float4* p = (const float4*)(in + sbase + (size_t)grow * WW + col0);
            cl[r] = p[0]; cr[r] = p[1];
            const float4* q = (const float4*)(xg + sbase + (size_t)grow * WW + col0);
            xl[r] = q[0]; xr_[r] = q[1];
        } else {
            cl[r] = neg4; cr[r] = neg4; xl[r] = one4; xr_[r] = one4;
        }
    }

    // horizontal 3-max of one 8-px row (a=cols0-3, b=cols4-7), DPP exchange
    auto hrow = [&](float4 a, float4 b) -> F8 {
        float lpx = dpp_up(b.w);       // left neighbor's col7; lane0 = -inf pad
        float rpx = dpp_dn(a.x);       // right neighbor's col0; lane63 = -inf pad
        F8 h;
        h.a.x = fmaxf(fmaxf(lpx, a.x), a.y);
        h.a.y = fmaxf(fmaxf(a.x, a.y), a.z);
        h.a.z = fmaxf(fmaxf(a.y, a.z), a.w);
        h.a.w = fmaxf(fmaxf(a.z, a.w), b.x);
        h.b.x = fmaxf(fmaxf(a.w, b.x), b.y);
        h.b.y = fmaxf(fmaxf(b.x, b.y), b.z);
        h.b.z = fmaxf(fmaxf(b.y, b.z), b.w);
        h.b.w = fmaxf(fmaxf(b.z, b.w), rpx);
        return h;
    };

    for (int t = 0; t < TSTEPS; ++t) {
        const int buf = t & 1;
        float* tp = &Tb[buf][ty][tx * 9];
        float* bp = &Bb[buf][ty][tx * 9];
        // snapshot pre-step top/bottom rows for vertical neighbors
        tp[0] = cl[0].x;  tp[1] = cl[0].y;  tp[2] = cl[0].z;  tp[3] = cl[0].w;
        tp[4] = cr[0].x;  tp[5] = cr[0].y;  tp[6] = cr[0].z;  tp[7] = cr[0].w;
        bp[0] = cl[11].x; bp[1] = cl[11].y; bp[2] = cl[11].z; bp[3] = cl[11].w;
        bp[4] = cr[11].x; bp[5] = cr[11].y; bp[6] = cr[11].z; bp[7] = cr[11].w;
        __syncthreads();

        float4 upA, upB, dnA, dnB;
        if (ty > 0) {                    // wave-uniform
            const float* q = &Bb[buf][ty - 1][tx * 9];
            upA = make_float4(q[0], q[1], q[2], q[3]);
            upB = make_float4(q[4], q[5], q[6], q[7]);
        } else { upA = neg4; upB = neg4; }
        if (ty < TY - 1) {
            const float* q = &Tb[buf][ty + 1][tx * 9];
            dnA = make_float4(q[0], q[1], q[2], q[3]);
            dnB = make_float4(q[4], q[5], q[6], q[7]);
        } else { dnA = neg4; dnB = neg4; }

        F8 hA = hrow(upA, upB);          // row r-1 (neighbor)
        F8 hB = hrow(cl[0], cr[0]);      // row r
#pragma unroll
        for (int r = 0; r < ROWS; ++r) {
            F8 hC;
            if (r + 1 < ROWS) hC = hrow(cl[r + 1], cr[r + 1]);
            else              hC = hrow(dnA, dnB);
            float4 vl, vr;
            vl.x = fmaxf(fmaxf(hA.a.x, hB.a.x), hC.a.x);
            vl.y = fmaxf(fmaxf(hA.a.y, hB.a.y), hC.a.y);
            vl.z = fmaxf(fmaxf(hA.a.z, hB.a.z), hC.a.z);
            vl.w = fmaxf(fmaxf(hA.a.w, hB.a.w), hC.a.w);
            vr.x = fmaxf(fmaxf(hA.b.x, hB.b.x), hC.b.x);
            vr.y = fmaxf(fmaxf(hA.b.y, hB.b.y), hC.b.y);
            vr.z = fmaxf(fmaxf(hA.b.z, hB.b.z), hC.b.z);
            vr.w = fmaxf(fmaxf(hA.b.w, hB.b.w), hC.b.w);
            cl[r].x = vl.x * xl[r].x;  cl[r].y = vl.y * xl[r].y;
            cl[r].z = vl.z * xl[r].z;  cl[r].w = vl.w * xl[r].w;
            cr[r].x = vr.x * xr_[r].x; cr[r].y = vr.y * xr_[r].y;
            cr[r].z = vr.z * xr_[r].z; cr[r].w = vr.w * xr_[r].w;
            hA = hB; hB = hC;
        }
        // rows outside the image must be -inf before the next step's reads
#pragma unroll
        for (int r = 0; r < ROWS; ++r) {
            int grow = row0 + r;
            if (grow < 0 || grow >= HH) { cl[r] = neg4; cr[r] = neg4; }  // uniform
        }
        // no trailing barrier: next step writes the OTHER buffer; this
        // buffer is rewritten only at step t+2, after barrier t+1.
    }

    // store valid center rows: tile rows a in [TSTEPS, TSTEPS+RROWS)
#pragma unroll
    for (int r = 0; r < ROWS; ++r) {
        int a = ty * ROWS + r;           // wave-uniform condition
        if (a >= TSTEPS && a < TSTEPS + RROWS) {
            int grow = row0 + r;
            float4* p = (float4*)(out + sbase + (size_t)grow * WW + col0);
            p[0] = cl[r]; p[1] = cr[r];
        }
    }
}

// ---------------------------------------------------------------------------
// final: norm over channel dim (19), out = cur * x / max(||cur||_2, eps)
__global__ void norm_kernel(const float* __restrict__ cur,
                            const float* __restrict__ x,
                            float* __restrict__ out) {
    int t = blockIdx.x * blockDim.x + threadIdx.x;
    int j4 = t & (W4 - 1);
    int i  = (t >> 7) & (HH - 1);
    int b  = t >> 16;
    size_t off = (size_t)b * CC * SLICE + (size_t)i * WW + (j4 << 2);

    float4 vals[CC];
    float sx = 0.f, sy = 0.f, sz = 0.f, sw = 0.f;
#pragma unroll
    for (int c = 0; c < CC; ++c) {
        float4 v = *(const float4*)(cur + off + (size_t)c * SLICE);
        vals[c] = v;
        sx += v.x * v.x; sy += v.y * v.y; sz += v.z * v.z; sw += v.w * v.w;
    }
    float4 r;
    r.x = 1.0f / fmaxf(sqrtf(sx), EPS);
    r.y = 1.0f / fmaxf(sqrtf(sy), EPS);
    r.z = 1.0f / fmaxf(sqrtf(sz), EPS);
    r.w = 1.0f / fmaxf(sqrtf(sw), EPS);
#pragma unroll
    for (int c = 0; c < CC; ++c) {
        float4 xv = *(const float4*)(x + off + (size_t)c * SLICE);
        float4 o;
        o.x = vals[c].x * xv.x * r.x;
        o.y = vals[c].y * xv.y * r.y;
        o.z = vals[c].z * xv.z * r.z;
        o.w = vals[c].w * xv.w * r.w;
        *(float4*)(out + off + (size_t)c * SLICE) = o;
    }
}

// ---------------------------------------------------------------------------
extern "C" void kernel_launch(void* const* d_in, const int* in_sizes, int n_in,
                              void* d_out, int out_size, void* d_ws, size_t ws_size,
                              hipStream_t stream) {
    const float* x = (const float*)d_in[0];
    float* out = (float*)d_out;
    float* ws  = (float*)d_ws;        // >= 79,691,776 B

    const int initBlocks = NSLICE * SLICE / 4 / 256; // 19456
    const int passBlocks = NSLICE * RBLK;            // 608
    const int normBlocks = BB * HH * W4 / 256;       // 1024

    init_kernel<<<initBlocks, 256, 0, stream>>>(x, ws);
    float* a = ws;
    float* b = out;
    for (int it = 0; it < NPASS; ++it) {
        pass_kernel<<<passBlocks, THREADS, 0, stream>>>(a, x, b);
        float* tmp = a; a = b; b = tmp;
    }
    // NPASS even -> result back in ws
    norm_kernel<<<normBlocks, 256, 0, stream>>>(ws, x, out);
}

// Round 8
// 2073.638 us; speedup vs baseline: 2.1824x; 1.0698x over previous
//
#include <hip/hip_runtime.h>
#include <math.h>

// Problem constants (4, 19, 512, 512) fp32
#define BB 4
#define CC 19
#define HH 512
#define WW 512
#define NSLICE (BB * CC)        // 76
#define SLICE  (HH * WW)        // 262144
#define W4     (WW / 4)         // 128 float4 per row
#define EPS    1e-12f
#define NEGINF (-INFINITY)

// time-tiling params
#define TSTEPS 16
#define NPASS  16               // 256 / TSTEPS

// Balanced grid (R8): 608 equal tiles gave ceil(608/256)=3 serial block-waves
// (makespan 3x96=288 row-units; 160 CUs idle in wave 3; R7 measured
// 135us = 3 x 45us/block exactly). New mix: 512 big tiles (64-out/96-in)
// + 192 small (32-out/64-in) = 704 blocks, big-first dispatch ->
// waves 1-2 big (96 units) + wave 3 small (64 units) = 256 units (-11%).
// Coverage: slices 0..27 = 8x64 rows; slices 28..75 = 6x64 + 4x32.
#define NBIG   512
#define NSMALL 192

// thread geometry: 64 lanes x (8 cols each) x 8 waves; rows/thread is a
// template param (12 big / 8 small) so ALL loop trips stay compile-time
// (R2/R3 lesson: dynamic bounds -> scratch spill).
//
// PROVEN on this problem (R0-R7):
//  * Register budget: T threads -> ceil(T/64/4) waves/EU -> 512/that total
//    regs (half arch-VGPR half AGPR). 512thr = 256 total; the 192-float
//    c+x state allocates CLEAN only with R0's rolling hA/hB/hC body
//    (each row consumed once). Deviations spilled (R1-R4, R6) or thrashed
//    L2 (R5 x-streaming: 815MB fetch/pass).
//  * Tile c+x state = 75% of CU register file regardless of partition ->
//    2 waves/SIMD and 1 block/CU are structural; no co-residency.
//  * __shfl == ds_bpermute (DS latency, unhidden at 2 waves/SIMD). DPP
//    wave_shr/shl:1 with old=-inf does the halo exchange in full-rate VALU
//    AND gives the image-pad for free (R7: 158.7 -> 135.5us/pass).
//  * Double-buffered LDS halo snapshot -> ONE __syncthreads per step.
//  * XCD-chunked bijective swizzle keeps a slice's row-blocks on one XCD
//    (R7: FETCH 118 -> 105 MB).
#define TX   64
#define TY   8
#define COLS 8
#define THREADS 512

struct F8 { float4 a, b; };

// DPP lane shifts (gfx9-family wave_shr:1 / wave_shl:1, valid on gfx950).
// bound_ctrl=false keeps `old` in the edge lane -> -inf image pad for free.
__device__ __forceinline__ float dpp_up(float src) {   // lane i <- lane i-1; lane0 -> -inf
    int o = __builtin_amdgcn_update_dpp(__float_as_int(NEGINF), __float_as_int(src),
                                        0x138 /*wave_shr:1*/, 0xF, 0xF, false);
    return __int_as_float(o);
}
__device__ __forceinline__ float dpp_dn(float src) {   // lane i <- lane i+1; lane63 -> -inf
    int o = __builtin_amdgcn_update_dpp(__float_as_int(NEGINF), __float_as_int(src),
                                        0x130 /*wave_shl:1*/, 0xF, 0xF, false);
    return __int_as_float(o);
}

// ---------------------------------------------------------------------------
__global__ void init_kernel(const float* __restrict__ x, float* __restrict__ cur) {
    int t = blockIdx.x * blockDim.x + threadIdx.x;
    const float4* x4 = (const float4*)x;
    float4* c4 = (float4*)cur;
    float4 v = x4[t];
    int pix = t << 2;
    int s = pix & (SLICE - 1);
    int i = s >> 9;
    int j0 = s & 511;
    float4 o;
    o.x = -v.x; o.y = -v.y; o.z = -v.z; o.w = -v.w;
    if (i == 0 || i == HH - 1) {
        o.x = 1.0f; o.y = 1.0f; o.z = 1.0f; o.w = 1.0f;
    } else {
        if (j0 == 0)        o.x = 1.0f;
        if (j0 == WW - 4)   o.w = 1.0f;
    }
    c4[t] = o;
}

// ---------------------------------------------------------------------------
// one tile = TSTEPS fused (maxpool3x3 * x) steps on a 512 x (8R) tile.
// R = rows/thread (compile-time), RR = valid output rows = 8R - 32.
// Body is R7's proven structure verbatim.
template<int R, int RR>
__device__ __forceinline__ void pass_body(const float* __restrict__ in,
                                          const float* __restrict__ xg,
                                          float* __restrict__ out,
                                          int bc, int tr0,
                                          float (&Tb)[2][TY][TX * 9],
                                          float (&Bb)[2][TY][TX * 9]) {
    const int tid  = threadIdx.x;
    const int tx   = tid & 63;          // lane = column group
    const int ty   = tid >> 6;          // wave = thread-row
    const int gstart = tr0 - TSTEPS;    // tile row a=0 -> global row
    const int row0   = gstart + ty * R; // this thread's r=0 global row
    const int col0   = tx * COLS;
    const size_t sbase = (size_t)bc * SLICE;

    const float4 neg4 = make_float4(NEGINF, NEGINF, NEGINF, NEGINF);
    const float4 one4 = make_float4(1.f, 1.f, 1.f, 1.f);

    float4 cl[R], cr[R], xl[R], xr_[R];

#pragma unroll
    for (int r = 0; r < R; ++r) {
        int grow = row0 + r;
        if (grow >= 0 && grow < HH) {               // wave-uniform branch
            const float4* p = (const float4*)(in + sbase + (size_t)grow * WW + col0);
            cl[r] = p[0]; cr[r] = p[1];
            const float4* q = (const float4*)(xg + sbase + (size_t)grow * WW + col0);
            xl[r] = q[0]; xr_[r] = q[1];
        } else {
            cl[r] = neg4; cr[r] = neg4; xl[r] = one4; xr_[r] = one4;
        }
    }

    // horizontal 3-max of one 8-px row (a=cols0-3, b=cols4-7), DPP exchange
    auto hrow = [&](float4 a, float4 b) -> F8 {
        float lpx = dpp_up(b.w);       // left neighbor's col7; lane0 = -inf pad
        float rpx = dpp_dn(a.x);       // right neighbor's col0; lane63 = -inf pad
        F8 h;
        h.a.x = fmaxf(fmaxf(lpx, a.x), a.y);
        h.a.y = fmaxf(fmaxf(a.x, a.y), a.z);
        h.a.z = fmaxf(fmaxf(a.y, a.z), a.w);
        h.a.w = fmaxf(fmaxf(a.z, a.w), b.x);
        h.b.x = fmaxf(fmaxf(a.w, b.x), b.y);
        h.b.y = fmaxf(fmaxf(b.x, b.y), b.z);
        h.b.z = fmaxf(fmaxf(b.y, b.z), b.w);
        h.b.w = fmaxf(fmaxf(b.z, b.w), rpx);
        return h;
    };

    for (int t = 0; t < TSTEPS; ++t) {
        const int buf = t & 1;
        float* tp = &Tb[buf][ty][tx * 9];
        float* bp = &Bb[buf][ty][tx * 9];
        // snapshot pre-step top/bottom rows for vertical neighbors
        tp[0] = cl[0].x;      tp[1] = cl[0].y;      tp[2] = cl[0].z;      tp[3] = cl[0].w;
        tp[4] = cr[0].x;      tp[5] = cr[0].y;      tp[6] = cr[0].z;      tp[7] = cr[0].w;
        bp[0] = cl[R - 1].x;  bp[1] = cl[R - 1].y;  bp[2] = cl[R - 1].z;  bp[3] = cl[R - 1].w;
        bp[4] = cr[R - 1].x;  bp[5] = cr[R - 1].y;  bp[6] = cr[R - 1].z;  bp[7] = cr[R - 1].w;
        __syncthreads();

        float4 upA, upB, dnA, dnB;
        if (ty > 0) {                    // wave-uniform
            const float* q = &Bb[buf][ty - 1][tx * 9];
            upA = make_float4(q[0], q[1], q[2], q[3]);
            upB = make_float4(q[4], q[5], q[6], q[7]);
        } else { upA = neg4; upB = neg4; }
        if (ty < TY - 1) {
            const float* q = &Tb[buf][ty + 1][tx * 9];
            dnA = make_float4(q[0], q[1], q[2], q[3]);
            dnB = make_float4(q[4], q[5], q[6], q[7]);
        } else { dnA = neg4; dnB = neg4; }

        F8 hA = hrow(upA, upB);          // row r-1 (neighbor)
        F8 hB = hrow(cl[0], cr[0]);      // row r
#pragma unroll
        for (int r = 0; r < R; ++r) {
            F8 hC;
            if (r + 1 < R) hC = hrow(cl[r + 1], cr[r + 1]);
            else           hC = hrow(dnA, dnB);
            float4 vl, vr;
            vl.x = fmaxf(fmaxf(hA.a.x, hB.a.x), hC.a.x);
            vl.y = fmaxf(fmaxf(hA.a.y, hB.a.y), hC.a.y);
            vl.z = fmaxf(fmaxf(hA.a.z, hB.a.z), hC.a.z);
            vl.w = fmaxf(fmaxf(hA.a.w, hB.a.w), hC.a.w);
            vr.x = fmaxf(fmaxf(hA.b.x, hB.b.x), hC.b.x);
            vr.y = fmaxf(fmaxf(hA.b.y, hB.b.y), hC.b.y);
            vr.z = fmaxf(fmaxf(hA.b.z, hB.b.z), hC.b.z);
            vr.w = fmaxf(fmaxf(hA.b.w, hB.b.w), hC.b.w);
            cl[r].x = vl.x * xl[r].x;  cl[r].y = vl.y * xl[r].y;
            cl[r].z = vl.z * xl[r].z;  cl[r].w = vl.w * xl[r].w;
            cr[r].x = vr.x * xr_[r].x; cr[r].y = vr.y * xr_[r].y;
            cr[r].z = vr.z * xr_[r].z; cr[r].w = vr.w * xr_[r].w;
            hA = hB; hB = hC;
        }
        // rows outside the image must be -inf before the next step's reads
#pragma unroll
        for (int r = 0; r < R; ++r) {
            int grow = row0 + r;
            if (grow < 0 || grow >= HH) { cl[r] = neg4; cr[r] = neg4; }  // uniform
        }
        // no trailing barrier: next step writes the OTHER buffer; this
        // buffer is rewritten only at step t+2, after barrier t+1.
    }

    // store valid center rows: tile rows a in [TSTEPS, TSTEPS+RR)
#pragma unroll
    for (int r = 0; r < R; ++r) {
        int a = ty * R + r;              // wave-uniform condition
        if (a >= TSTEPS && a < TSTEPS + RR) {
            int grow = row0 + r;
            float4* p = (float4*)(out + sbase + (size_t)grow * WW + col0);
            p[0] = cl[r]; p[1] = cr[r];
        }
    }
}

// ---------------------------------------------------------------------------
__global__ __launch_bounds__(THREADS, 1)
void pass_kernel(const float* __restrict__ in, const float* __restrict__ xg,
                 float* __restrict__ out) {
    // LDS halo exchange: 8 floats per thread, 9-word lane stride (proven
    // layout), double-buffered -> one barrier per step. 72 KiB.
    __shared__ float Tb[2][TY][TX * 9];
    __shared__ float Bb[2][TY][TX * 9];

    const int bid = blockIdx.x;
    if (bid < NBIG) {
        // big tiles: 64-out/96-in. Bijective XCD swizzle over 512 = 8 x 64.
        const int g = (bid & 7) * (NBIG / 8) + (bid >> 3);
        int bc, tr0;
        if (g < 28 * 8) {                // slices 0..27: 8 big tiles each
            bc  = g >> 3;
            tr0 = (g & 7) << 6;
        } else {                         // slices 28..75: 6 big tiles each
            int g2 = g - 28 * 8;
            bc  = 28 + g2 / 6;
            tr0 = (g2 % 6) << 6;
        }
        pass_body<12, 64>(in, xg, out, bc, tr0, Tb, Bb);
    } else {
        // small tiles: 32-out/64-in, rows [384,512) of slices 28..75.
        // Bijective XCD swizzle over 192 = 8 x 24.
        const int sb = bid - NBIG;
        const int h  = (sb & 7) * (NSMALL / 8) + (sb >> 3);
        const int bc  = 28 + (h >> 2);
        const int tr0 = 384 + ((h & 3) << 5);
        pass_body<8, 32>(in, xg, out, bc, tr0, Tb, Bb);
    }
}

// ---------------------------------------------------------------------------
// final: norm over channel dim (19), out = cur * x / max(||cur||_2, eps)
__global__ void norm_kernel(const float* __restrict__ cur,
                            const float* __restrict__ x,
                            float* __restrict__ out) {
    int t = blockIdx.x * blockDim.x + threadIdx.x;
    int j4 = t & (W4 - 1);
    int i  = (t >> 7) & (HH - 1);
    int b  = t >> 16;
    size_t off = (size_t)b * CC * SLICE + (size_t)i * WW + (j4 << 2);

    float4 vals[CC];
    float sx = 0.f, sy = 0.f, sz = 0.f, sw = 0.f;
#pragma unroll
    for (int c = 0; c < CC; ++c) {
        float4 v = *(const float4*)(cur + off + (size_t)c * SLICE);
        vals[c] = v;
        sx += v.x * v.x; sy += v.y * v.y; sz += v.z * v.z; sw += v.w * v.w;
    }
    float4 r;
    r.x = 1.0f / fmaxf(sqrtf(sx), EPS);
    r.y = 1.0f / fmaxf(sqrtf(sy), EPS);
    r.z = 1.0f / fmaxf(sqrtf(sz), EPS);
    r.w = 1.0f / fmaxf(sqrtf(sw), EPS);
#pragma unroll
    for (int c = 0; c < CC; ++c) {
        float4 xv = *(const float4*)(x + off + (size_t)c * SLICE);
        float4 o;
        o.x = vals[c].x * xv.x * r.x;
        o.y = vals[c].y * xv.y * r.y;
        o.z = vals[c].z * xv.z * r.z;
        o.w = vals[c].w * xv.w * r.w;
        *(float4*)(out + off + (size_t)c * SLICE) = o;
    }
}

// ---------------------------------------------------------------------------
extern "C" void kernel_launch(void* const* d_in, const int* in_sizes, int n_in,
                              void* d_out, int out_size, void* d_ws, size_t ws_size,
                              hipStream_t stream) {
    const float* x = (const float*)d_in[0];
    float* out = (float*)d_out;
    float* ws  = (float*)d_ws;        // >= 79,691,776 B

    const int initBlocks = NSLICE * SLICE / 4 / 256; // 19456
    const int passBlocks = NBIG + NSMALL;            // 704
    const int normBlocks = BB * HH * W4 / 256;       // 1024

    init_kernel<<<initBlocks, 256, 0, stream>>>(x, ws);
    float* a = ws;
    float* b = out;
    for (int it = 0; it < NPASS; ++it) {
        pass_kernel<<<passBlocks, THREADS, 0, stream>>>(a, x, b);
        float* tmp = a; a = b; b = tmp;
    }
    // NPASS even -> result back in ws
    norm_kernel<<<normBlocks, 256, 0, stream>>>(ws, x, out);
}